// Round 5
// baseline (372.900 us; speedup 1.0000x reference)
//
#include <hip/hip_runtime.h>
#include <hip/hip_bf16.h>
#include <cstdint>

typedef float v4f __attribute__((ext_vector_type(4)));
typedef float v2f __attribute__((ext_vector_type(2)));
typedef short s8v __attribute__((ext_vector_type(8)));
typedef unsigned short u16;

// ---------------------------------------------------------------------------
// ws layout (bytes):
//   [0, 442368)        wsB: bf16 MFMA B-fragments, per level (73728 u16):
//                        cls  [ks 0..7][nt 0..4][hl 0..1][lane 0..63][j 0..7]
//                        reg  (offset +40960 u16) [ks][nt 0..3][hl][lane][j]
//                      element: o = nt*16 + (lane&15), k = ks*32 + (lane>>4)*8 + j
//                      hl=0: bf16(w), hl=1: bf16(w - float(bf16(w)))
//   [442368, 444096)   biasf fp32 [3][144]: cls o=0..79, reg at 80+o
// ---------------------------------------------------------------------------
#define WSB_LVL     73728
#define WSB_CLS_SZ  40960
#define BIAS_OFF_B  442368

__device__ __forceinline__ u16 bfbits(float x) {
  return __builtin_bit_cast(u16, __float2bfloat16(x));
}
__device__ __forceinline__ float bff(u16 b) {
  return __builtin_bit_cast(float, ((unsigned int)b) << 16);
}
__device__ __forceinline__ unsigned int packhi(float a, float b) {
  return (unsigned int)bfbits(a) | ((unsigned int)bfbits(b) << 16);
}
__device__ __forceinline__ unsigned int packlo(float a, float b) {
  const float ra = a - bff(bfbits(a));
  const float rb = b - bff(bfbits(b));
  return packhi(ra, rb);
}
__device__ __forceinline__ v4f mfma16(s8v a, s8v b, v4f c) {
  return __builtin_amdgcn_mfma_f32_16x16x32_bf16(a, b, c, 0, 0, 0);
}

// Barrier that does NOT drain vmcnt: LDS visibility via lgkmcnt(0) on the
// issuing side; global loads (A-prefetch, B-fragments) stay in flight.
// "memory" clobbers fence LDS ops on both sides (rule: don't let ds ops
// migrate across the barrier at schedule time).
__device__ __forceinline__ void block_sync_lgkm() {
  asm volatile("s_waitcnt lgkmcnt(0)" ::: "memory");
  __builtin_amdgcn_s_barrier();
  asm volatile("" ::: "memory");
}

// ---------------------------------------------------------------------------
__global__ __launch_bounds__(256) void prep_weights(
    const float* __restrict__ cw0, const float* __restrict__ cb0,
    const float* __restrict__ rw0, const float* __restrict__ rb0,
    const float* __restrict__ cw1, const float* __restrict__ cb1,
    const float* __restrict__ rw1, const float* __restrict__ rb1,
    const float* __restrict__ cw2, const float* __restrict__ cb2,
    const float* __restrict__ rw2, const float* __restrict__ rb2,
    void* __restrict__ wsv)
{
  u16* wsB = (u16*)wsv;
  float* biasf = (float*)((char*)wsv + BIAS_OFF_B);
  const int gid = blockIdx.x * 256 + threadIdx.x;
  const float* cws[3] = {cw0, cw1, cw2};
  const float* cbs[3] = {cb0, cb1, cb2};
  const float* rws[3] = {rw0, rw1, rw2};
  const float* rbs[3] = {rb0, rb1, rb2};

  if (gid < 3 * WSB_LVL) {
    const int l = gid / WSB_LVL;
    int r = gid - l * WSB_LVL;
    const bool cls = r < WSB_CLS_SZ;
    if (!cls) r -= WSB_CLS_SZ;
    const int j    = r & 7;
    const int lane = (r >> 3) & 63;
    const int hl   = (r >> 9) & 1;
    int nt, ks;
    if (cls) { const int v = r >> 10; nt = v % 5; ks = v / 5; }
    else     { nt = (r >> 10) & 3; ks = r >> 12; }
    const int o = nt * 16 + (lane & 15);
    const int k = ks * 32 + (lane >> 4) * 8 + j;
    const float* w = cls ? cws[l] : rws[l];
    const float v = w[o * 256 + k];
    u16 bits;
    if (hl == 0) bits = bfbits(v);
    else         bits = bfbits(v - bff(bfbits(v)));
    wsB[gid] = bits;
  } else if (gid < 3 * WSB_LVL + 432) {
    const int i = gid - 3 * WSB_LVL;
    const int l = i / 144;
    const int o = i - l * 144;
    biasf[l * 144 + o] = (o < 80) ? cbs[l][o] : rbs[l][o - 80];
  }
}

// ---------------------------------------------------------------------------
// Split-bf16 MFMA GEMM over one 128-pixel tile, K=256 (8 K-steps of 32).
// A staged in LDS [128][72 bf16] (hi k0..31, lo at +32), 144B row stride.
// Issue order per K-step (FIFO vmcnt discipline):
//   1. B-fragments (10 loads, oldest)  -> MFMA waits vmcnt(4), A keeps flying
//   2. ds_write A(ks) (waits counted vmcnt for prev-iter A regs only)
//   3. A-prefetch(ks+1) (youngest)     -> consumed at next iter's ds_write
// Barriers are lgkm-only: vmcnt survives across them.
// ---------------------------------------------------------------------------
template<int NT>
__device__ __forceinline__ void gemm_accum(const float* __restrict__ feat,
                                           const u16* __restrict__ wB,
                                           u16* Abuf, const int t,
                                           const int m0, const int M,
                                           v4f (&acc)[2][NT])
{
  const int kp   = t & 15;       // k-pair 0..15 (k = 2*kp, 2*kp+1)
  const int mq0  = t >> 4;       // m-quad 0..15 (packet B: +16)
  const int mmA  = min(m0 + mq0 * 4, M - 4);
  const int mmB  = min(m0 + (mq0 + 16) * 4, M - 4);
  const int lane   = t & 63;
  const int lane15 = lane & 15;
  const int kg     = lane >> 4;
  const int mbase  = (t >> 6) * 32;
  unsigned int* AbufW = (unsigned int*)Abuf;
  const int w0 = (mq0 * 4) * 36 + kp;          // uint index, rows j add 36
  const int w1 = ((mq0 + 16) * 4) * 36 + kp;

  v4f r0a = *(const v4f*)(feat + (size_t)(2 * kp) * M + mmA);
  v4f r0b = *(const v4f*)(feat + (size_t)(2 * kp + 1) * M + mmA);
  v4f r1a = *(const v4f*)(feat + (size_t)(2 * kp) * M + mmB);
  v4f r1b = *(const v4f*)(feat + (size_t)(2 * kp + 1) * M + mmB);

#pragma unroll
  for (int ks = 0; ks < 8; ++ks) {
    // ---- 1. B-fragments for THIS K-step, issued first (oldest) ----
    s8v bh[NT], bl[NT];
#pragma unroll
    for (int nt = 0; nt < NT; ++nt) {
      const u16* bp = wB + (size_t)((ks * NT + nt) * 2) * 512 + lane * 8;
      bh[nt] = *(const s8v*)(bp);
      bl[nt] = *(const s8v*)(bp + 512);
    }
    // ---- 2. stage A(ks) into LDS (2-lanes/bank writes: free) ----
#pragma unroll
    for (int j = 0; j < 4; ++j) {
      AbufW[w0 + j * 36]      = packhi(r0a[j], r0b[j]);
      AbufW[w0 + j * 36 + 16] = packlo(r0a[j], r0b[j]);
      AbufW[w1 + j * 36]      = packhi(r1a[j], r1b[j]);
      AbufW[w1 + j * 36 + 16] = packlo(r1a[j], r1b[j]);
    }
    // ---- 3. prefetch A(ks+1), youngest ----
    if (ks < 7) {
      const size_t ko = (size_t)((ks + 1) * 32 + 2 * kp) * M;
      r0a = *(const v4f*)(feat + ko + mmA);
      r0b = *(const v4f*)(feat + ko + M + mmA);
      r1a = *(const v4f*)(feat + ko + mmB);
      r1b = *(const v4f*)(feat + ko + M + mmB);
    }
    block_sync_lgkm();
    // ---- A-fragments (ds_read_b128 x4) ----
    const u16* arow0 = Abuf + (mbase + lane15) * 72 + kg * 8;
    const u16* arow1 = Abuf + (mbase + 16 + lane15) * 72 + kg * 8;
    const s8v ahi0 = *(const s8v*)(arow0);
    const s8v alo0 = *(const s8v*)(arow0 + 32);
    const s8v ahi1 = *(const s8v*)(arow1);
    const s8v alo1 = *(const s8v*)(arow1 + 32);
    // ---- split-bf16 MFMA (B already in regs; waits vmcnt(4) at most) ----
    __builtin_amdgcn_s_setprio(1);
#pragma unroll
    for (int nt = 0; nt < NT; ++nt) {
      acc[0][nt] = mfma16(ahi0, bh[nt], acc[0][nt]);
      acc[0][nt] = mfma16(ahi0, bl[nt], acc[0][nt]);
      acc[0][nt] = mfma16(alo0, bh[nt], acc[0][nt]);
      acc[1][nt] = mfma16(ahi1, bh[nt], acc[1][nt]);
      acc[1][nt] = mfma16(ahi1, bl[nt], acc[1][nt]);
      acc[1][nt] = mfma16(alo1, bh[nt], acc[1][nt]);
    }
    __builtin_amdgcn_s_setprio(0);
    block_sync_lgkm();   // protects Abuf for next iteration's ds_write
  }
}

// ---------------------------------------------------------------------------
// LDS: Abuf only, 18432 B -> LDS allows 8 blocks/CU; VGPR cap 128 -> ~4.
// Epilogue stores directly to global (no ostage): 4x64B segments per store
// inst for cls, predicated v4f for box.
// ---------------------------------------------------------------------------
__global__ __launch_bounds__(256, 4) void head_kernel(
    const float* __restrict__ cf0, const float* __restrict__ rf0,
    const float* __restrict__ cf1, const float* __restrict__ rf1,
    const float* __restrict__ cf2, const float* __restrict__ rf2,
    const void* __restrict__ wsv, float* __restrict__ out)
{
  __shared__ __align__(16) u16 Abuf[128 * 72];

  const u16*   wsB   = (const u16*)wsv;
  const float* biasf = (const float*)((const char*)wsv + BIAS_OFF_B);

  const int t   = threadIdx.x;
  const int bid = blockIdx.x;

  int l, r;
  if (bid < 800)       { l = 0; r = bid; }
  else if (bid < 1008) { l = 1; r = bid - 800; }
  else                 { l = 2; r = bid - 1008; }

  const int tiles = (l == 0) ? 50 : (l == 1) ? 13 : 4;
  const int M     = (l == 0) ? 6400 : (l == 1) ? 1600 : 400;
  const int W     = (l == 0) ? 80 : (l == 1) ? 40 : 20;
  const int moff  = (l == 0) ? 0 : (l == 1) ? 6400 : 8000;
  const float sv  = (float)(8 << l);

  const int b    = r / tiles;
  const int tile = r - b * tiles;
  const int m0   = tile * 128;

  const float* cfL = (l == 0) ? cf0 : (l == 1) ? cf1 : cf2;
  const float* rfL = (l == 0) ? rf0 : (l == 1) ? rf1 : rf2;
  const float* featR = rfL + (size_t)b * 256 * (size_t)M;
  const float* featC = cfL + (size_t)b * 256 * (size_t)M;
  const u16* wBcls = wsB + l * WSB_LVL;
  const u16* wBreg = wsB + l * WSB_LVL + WSB_CLS_SZ;
  const int loff = l * 144;

  const int lane   = t & 63;
  const int lane15 = lane & 15;
  const int kg     = lane >> 4;
  const int mbase  = (t >> 6) * 32;

  float* const orow0 = out + ((size_t)b * 8400 + moff + m0) * 84;

  // ======================= reg GEMM (64 outs = 4 sides x 16 bins) ==========
  v4f accR[2][4];
#pragma unroll
  for (int mr = 0; mr < 2; ++mr)
#pragma unroll
    for (int nt = 0; nt < 4; ++nt) accR[mr][nt] = (v4f){0.f, 0.f, 0.f, 0.f};
  gemm_accum<4>(featR, wBreg, Abuf, t, m0, M, accR);

  float bR[4];
#pragma unroll
  for (int f = 0; f < 4; ++f) bR[f] = biasf[loff + 80 + f * 16 + lane15];

  // ======================= DFL: softmax over bins = over 16-lane group =====
  // C-frag col (lane&15) = bin, nt = side, row (kg*4+rr) = pixel.
  float d[2][4][4];
#pragma unroll
  for (int mr = 0; mr < 2; ++mr) {
#pragma unroll
    for (int f = 0; f < 4; ++f) {
#pragma unroll
      for (int rr = 0; rr < 4; ++rr) {
        const float xx = accR[mr][f][rr] + bR[f];
        float mx = xx;
        mx = fmaxf(mx, __shfl_xor(mx, 1));
        mx = fmaxf(mx, __shfl_xor(mx, 2));
        mx = fmaxf(mx, __shfl_xor(mx, 4));
        mx = fmaxf(mx, __shfl_xor(mx, 8));
        const float e = __expf(xx - mx);
        float s = e, wq = e * (float)lane15;
        s += __shfl_xor(s, 1); wq += __shfl_xor(wq, 1);
        s += __shfl_xor(s, 2); wq += __shfl_xor(wq, 2);
        s += __shfl_xor(s, 4); wq += __shfl_xor(wq, 4);
        s += __shfl_xor(s, 8); wq += __shfl_xor(wq, 8);
        d[mr][f][rr] = wq * (16.0f / 15.0f) / s;   // proj[q] = 16q/15
      }
    }
  }

  // box -> direct global store (predicated; every group lane has all sides)
#pragma unroll
  for (int mr = 0; mr < 2; ++mr) {
#pragma unroll
    for (int rr = 0; rr < 4; ++rr) {
      if (lane15 == mr * 4 + rr) {
        const int pl = mbase + mr * 16 + kg * 4 + rr;
        if (m0 + pl < M) {
          const int pg = m0 + pl;
          const int hh = pg / W;
          const int wc = pg - hh * W;
          const float ax = ((float)wc + 0.5f) * sv;
          const float ay = ((float)hh + 0.5f) * sv;
          v4f bb;
          bb[0] = ax - d[mr][0][rr] * sv;
          bb[1] = ay - d[mr][1][rr] * sv;
          bb[2] = ax + d[mr][2][rr] * sv;
          bb[3] = ay + d[mr][3][rr] * sv;
          *(v4f*)(orow0 + (size_t)pl * 84 + 80) = bb;
        }
      }
    }
  }

  // ======================= cls GEMM (80 outs = 5 n-tiles) ==================
  v4f accC[2][5];
#pragma unroll
  for (int mr = 0; mr < 2; ++mr)
#pragma unroll
    for (int nt = 0; nt < 5; ++nt) accC[mr][nt] = (v4f){0.f, 0.f, 0.f, 0.f};
  gemm_accum<5>(featC, wBcls, Abuf, t, m0, M, accC);

  float bC[5];
#pragma unroll
  for (int nt = 0; nt < 5; ++nt) bC[nt] = biasf[loff + nt * 16 + lane15];

  // sigmoid + direct stores (per inst: 4 rows x 64B contiguous segments)
#pragma unroll
  for (int mr = 0; mr < 2; ++mr) {
#pragma unroll
    for (int rr = 0; rr < 4; ++rr) {
      const int pl = mbase + mr * 16 + kg * 4 + rr;
      if (m0 + pl < M) {
        float* const prow = orow0 + (size_t)pl * 84;
#pragma unroll
        for (int nt = 0; nt < 5; ++nt) {
          const float z = accC[mr][nt][rr] + bC[nt];
          prow[nt * 16 + lane15] = 1.f / (1.f + __expf(-z));
        }
      }
    }
  }
}

// ---------------------------------------------------------------------------
extern "C" void kernel_launch(void* const* d_in, const int* in_sizes, int n_in,
                              void* d_out, int out_size, void* d_ws, size_t ws_size,
                              hipStream_t stream) {
  const float* cf[3]; const float* rff[3];
  const float* cw[3]; const float* cb[3];
  const float* rw[3]; const float* rb[3];
  for (int i = 0; i < 3; ++i) {
    cf[i]  = (const float*)d_in[i * 6 + 0];
    rff[i] = (const float*)d_in[i * 6 + 1];
    cw[i]  = (const float*)d_in[i * 6 + 2];
    cb[i]  = (const float*)d_in[i * 6 + 3];
    rw[i]  = (const float*)d_in[i * 6 + 4];
    rb[i]  = (const float*)d_in[i * 6 + 5];
  }
  float* o = (float*)d_out;

  // 3*73728 + 432 = 221616 work items -> 866 blocks
  prep_weights<<<dim3(866), dim3(256), 0, stream>>>(
      cw[0], cb[0], rw[0], rb[0],
      cw[1], cb[1], rw[1], rb[1],
      cw[2], cb[2], rw[2], rb[2], d_ws);

  head_kernel<<<dim3(1072), dim3(256), 0, stream>>>(
      cf[0], rff[0], cf[1], rff[1], cf[2], rff[2], d_ws, o);
}